// Round 1
// baseline (2599.148 us; speedup 1.0000x reference)
//
#include <hip/hip_runtime.h>
#include <hip/hip_bf16.h>

#define ROWS   16
#define TSTEPS 64
#define TT     65
#define DD     32
#define HH     128

__device__ __forceinline__ float tanh_fast(float x) {
    // tanh(x) = 1 - 2/(exp(2x)+1); exact saturation at +-1, ~1e-7 rel err
    float e = __expf(2.0f * x);
    return 1.0f - 2.0f / (e + 1.0f);
}

__global__ __launch_bounds__(256, 2)
void NeuralODE_dopri5_f32(const float* __restrict__ x, const float* __restrict__ t,
                          const float* __restrict__ W1, const float* __restrict__ b1,
                          const float* __restrict__ W2, const float* __restrict__ b2,
                          float* __restrict__ out) {
    __shared__ float sW1[DD][HH];   // sW1[d][c] = W1[c][d]  (transposed)
    __shared__ float sW2[HH][DD];   // sW2[c][d] = W2[d][c]  (transposed)
    __shared__ float sb1[HH];
    __shared__ float sb2[DD];
    __shared__ float sy [ROWS][DD];
    __shared__ float syt[ROWS][DD];
    __shared__ float sz [ROWS][HH];
    __shared__ float sk [6][ROWS][DD];

    const int tid = threadIdx.x;
    const size_t row0 = (size_t)blockIdx.x * ROWS;

    // ---- stage weights into LDS (transposed for contiguous col access) ----
    for (int i = tid; i < HH * DD; i += 256) {
        int c = i >> 5, d = i & 31;          // W1 is (H=128, D=32) row-major
        sW1[d][c] = W1[i];
    }
    for (int i = tid; i < DD * HH; i += 256) {
        int d = i >> 7, c = i & 127;         // W2 is (D=32, H=128) row-major
        sW2[c][d] = W2[i];
    }
    if (tid < HH) sb1[tid] = b1[tid];
    if (tid < DD) sb2[tid] = b2[tid];

    // ---- load y0 = x[:,0,:], also emit output step 0 ----
    for (int i = tid; i < ROWS * DD; i += 256) {
        int rr = i >> 5, d = i & 31;
        float v = x[(row0 + rr) * (TT * DD) + d];
        sy[rr][d] = v;
        out[(row0 + rr) * (TT * DD) + d] = v;
    }
    __syncthreads();

    // thread roles
    const int r  = tid >> 4;          // 0..15 : row
    const int q  = tid & 15;
    const int c0 = q * 8;             // m1: 8 hidden cols
    const int d0 = (q & 3) * 8;       // m2: 8 output dims
    const int cb = (q >> 2) * 32;     // m2: 32-wide hidden slice

    // Dopri5 tableau
    const float A[5][5] = {
        {0.2f, 0.f, 0.f, 0.f, 0.f},
        {3.f/40.f, 9.f/40.f, 0.f, 0.f, 0.f},
        {44.f/45.f, -56.f/15.f, 32.f/9.f, 0.f, 0.f},
        {19372.f/6561.f, -25360.f/2187.f, 64448.f/6561.f, -212.f/729.f, 0.f},
        {9017.f/3168.f, -355.f/33.f, 46732.f/5247.f, 49.f/176.f, -5103.f/18656.f}
    };

    for (int step = 0; step < TSTEPS; ++step) {
        const float h = t[step + 1] - t[step];   // uniform scalar loads (t row 0)

        #pragma unroll
        for (int s = 0; s < 6; ++s) {
            // ---- build stage argument ytmp = y + h * sum_j A[s-1][j] * k_j ----
            for (int i = tid; i < ROWS * DD; i += 256) {
                int rr = i >> 5, d = i & 31;
                float v = sy[rr][d];
                #pragma unroll
                for (int j = 0; j < 5; ++j) {
                    if (j < s) v += (h * A[s - 1][j]) * sk[j][rr][d];
                }
                syt[rr][d] = v;
            }
            __syncthreads();

            // ---- m1 + tanh: z[r][c] = tanh(ytmp[r]·W1[c] + b1[c]) ----
            {
                float yv[DD];
                #pragma unroll
                for (int i = 0; i < 8; ++i) {
                    float4 v = *(const float4*)&syt[r][i * 4];
                    yv[i*4+0] = v.x; yv[i*4+1] = v.y; yv[i*4+2] = v.z; yv[i*4+3] = v.w;
                }
                float acc[8];
                #pragma unroll
                for (int c = 0; c < 8; ++c) acc[c] = sb1[c0 + c];
                #pragma unroll
                for (int d = 0; d < DD; ++d) {
                    float4 wa = *(const float4*)&sW1[d][c0];
                    float4 wb = *(const float4*)&sW1[d][c0 + 4];
                    float yd = yv[d];
                    acc[0] += yd * wa.x; acc[1] += yd * wa.y;
                    acc[2] += yd * wa.z; acc[3] += yd * wa.w;
                    acc[4] += yd * wb.x; acc[5] += yd * wb.y;
                    acc[6] += yd * wb.z; acc[7] += yd * wb.w;
                }
                #pragma unroll
                for (int c = 0; c < 8; ++c) sz[r][c0 + c] = tanh_fast(acc[c]);
            }
            __syncthreads();

            // ---- m2: k_s[r][d] = z[r]·W2T[:,d] + b2[d] (4-way split over c) ----
            {
                float zv[32];
                #pragma unroll
                for (int i = 0; i < 8; ++i) {
                    float4 v = *(const float4*)&sz[r][cb + i * 4];
                    zv[i*4+0] = v.x; zv[i*4+1] = v.y; zv[i*4+2] = v.z; zv[i*4+3] = v.w;
                }
                float kacc[8] = {0.f,0.f,0.f,0.f,0.f,0.f,0.f,0.f};
                #pragma unroll
                for (int c = 0; c < 32; ++c) {
                    float4 wa = *(const float4*)&sW2[cb + c][d0];
                    float4 wb = *(const float4*)&sW2[cb + c][d0 + 4];
                    float zc = zv[c];
                    kacc[0] += zc * wa.x; kacc[1] += zc * wa.y;
                    kacc[2] += zc * wa.z; kacc[3] += zc * wa.w;
                    kacc[4] += zc * wb.x; kacc[5] += zc * wb.y;
                    kacc[6] += zc * wb.z; kacc[7] += zc * wb.w;
                }
                #pragma unroll
                for (int j = 0; j < 8; ++j) {
                    kacc[j] += __shfl_xor(kacc[j], 4, 64);
                    kacc[j] += __shfl_xor(kacc[j], 8, 64);
                }
                if (q < 4) {   // q == q&3 here, d0 = q*8
                    float4 o0, o1;
                    o0.x = kacc[0] + sb2[d0+0]; o0.y = kacc[1] + sb2[d0+1];
                    o0.z = kacc[2] + sb2[d0+2]; o0.w = kacc[3] + sb2[d0+3];
                    o1.x = kacc[4] + sb2[d0+4]; o1.y = kacc[5] + sb2[d0+5];
                    o1.z = kacc[6] + sb2[d0+6]; o1.w = kacc[7] + sb2[d0+7];
                    *(float4*)&sk[s][r][d0]     = o0;
                    *(float4*)&sk[s][r][d0 + 4] = o1;
                }
            }
            __syncthreads();
        }

        // ---- y_{n+1} = y + h*(b1 k1 + b3 k3 + b4 k4 + b5 k5 + b6 k6); emit ----
        const float hb1 = h * (35.f/384.f);
        const float hb3 = h * (500.f/1113.f);
        const float hb4 = h * (125.f/192.f);
        const float hb5 = h * (-2187.f/6784.f);
        const float hb6 = h * (11.f/84.f);
        for (int i = tid; i < ROWS * DD; i += 256) {
            int rr = i >> 5, d = i & 31;
            float v = sy[rr][d]
                    + hb1 * sk[0][rr][d] + hb3 * sk[2][rr][d]
                    + hb4 * sk[3][rr][d] + hb5 * sk[4][rr][d]
                    + hb6 * sk[5][rr][d];
            sy[rr][d] = v;
            out[(row0 + rr) * (TT * DD) + (size_t)(step + 1) * DD + d] = v;
        }
        __syncthreads();
    }
}

extern "C" void kernel_launch(void* const* d_in, const int* in_sizes, int n_in,
                              void* d_out, int out_size, void* d_ws, size_t ws_size,
                              hipStream_t stream) {
    const float* x  = (const float*)d_in[0];
    const float* t  = (const float*)d_in[1];
    // d_in[2] = itv, d_in[3] = itv_mask : unused by the reference math
    const float* W1 = (const float*)d_in[4];
    const float* b1 = (const float*)d_in[5];
    const float* W2 = (const float*)d_in[6];
    const float* b2 = (const float*)d_in[7];
    float* out = (float*)d_out;

    dim3 grid(8192 / ROWS);   // 512 blocks, each owns 16 independent ODEs
    dim3 block(256);
    hipLaunchKernelGGL(NeuralODE_dopri5_f32, grid, block, 0, stream,
                       x, t, W1, b1, W2, b2, out);
}

// Round 2
// 1410.980 us; speedup vs baseline: 1.8421x; 1.8421x over previous
//
#include <hip/hip_runtime.h>

#define TT 65
#define DD 32
#define HH 128
#define NSTEP 64

// Dopri5 tableau: AT[s][j] multiplies k_{j+1} in the stage-s argument; BT[s]
// multiplies stage-s output in the final combine. Row 0 is all zeros (k1 = f(y)).
__constant__ float AT[6][5] = {
    {0.f, 0.f, 0.f, 0.f, 0.f},
    {0.2f, 0.f, 0.f, 0.f, 0.f},
    {3.f/40.f, 9.f/40.f, 0.f, 0.f, 0.f},
    {44.f/45.f, -56.f/15.f, 32.f/9.f, 0.f, 0.f},
    {19372.f/6561.f, -25360.f/2187.f, 64448.f/6561.f, -212.f/729.f, 0.f},
    {9017.f/3168.f, -355.f/33.f, 46732.f/5247.f, 49.f/176.f, -5103.f/18656.f}
};
__constant__ float BT[6] = {35.f/384.f, 0.f, 500.f/1113.f, 125.f/192.f,
                            -2187.f/6784.f, 11.f/84.f};

__device__ __forceinline__ float tanh_fast(float x) {
    float e = __expf(2.0f * x);
    return 1.0f - 2.0f / (e + 1.0f);
}

// One wave = 4 independent ODE rows, processed as 2 pairs. Lane l:
//   d  = l & 31  : state dimension this lane owns
//   hf = l >> 5  : row-parity within a pair (also W2 half for m2)
// Weights live in registers: W1 rows (l, l+64) and W2[d][64*hf .. 64*hf+63].
// LDS: per-wave broadcast buffers only; no __syncthreads anywhere.
__global__ __launch_bounds__(256, 2)
void NeuralODE_dopri5_regw(const float* __restrict__ x, const float* __restrict__ t,
                           const float* __restrict__ W1, const float* __restrict__ b1,
                           const float* __restrict__ W2, const float* __restrict__ b2,
                           float* __restrict__ out)
{
    __shared__ __align__(16) float syt[4][2][DD];   // [wave][row-parity][d]
    __shared__ __align__(16) float sz [4][2][HH];   // [wave][row-in-pair][c]

    const int tid = threadIdx.x;
    const int wv  = tid >> 6;
    const int l   = tid & 63;
    const int d   = l & 31;
    const int hf  = l >> 5;

    // ---- weights -> registers ----
    float W1A[DD], W1B[DD], W2R[64];
    #pragma unroll
    for (int i = 0; i < 8; ++i) {
        float4 va = *(const float4*)&W1[(size_t)l * DD + 4 * i];          // W1 (H,D) row l
        float4 vb = *(const float4*)&W1[(size_t)(64 + l) * DD + 4 * i];   // row l+64
        W1A[4*i+0] = va.x; W1A[4*i+1] = va.y; W1A[4*i+2] = va.z; W1A[4*i+3] = va.w;
        W1B[4*i+0] = vb.x; W1B[4*i+1] = vb.y; W1B[4*i+2] = vb.z; W1B[4*i+3] = vb.w;
    }
    #pragma unroll
    for (int i = 0; i < 16; ++i) {
        float4 v = *(const float4*)&W2[(size_t)d * HH + 64 * hf + 4 * i]; // W2 (D,H)
        W2R[4*i+0] = v.x; W2R[4*i+1] = v.y; W2R[4*i+2] = v.z; W2R[4*i+3] = v.w;
    }
    const float b1A = b1[l];
    const float b1B = b1[64 + l];
    const float b2e = (hf == 0) ? b2[d] : 0.f;   // bias added on half 0 only (pre-reduce)

    // lane s holds h_s = t[s+1] - t[s]  (t row 0; l+1 <= 64 valid)
    const float h_all = t[l + 1] - t[l];

    const int rowbase = blockIdx.x * 16 + wv * 4;

    float y[2];
    float k[2][5];
    #pragma unroll
    for (int p = 0; p < 2; ++p) {
        size_t r = (size_t)(rowbase + 2 * p + hf);
        float v = x[r * (TT * DD) + d];
        y[p] = v;
        out[r * (TT * DD) + d] = v;          // step-0 output
        #pragma unroll
        for (int j = 0; j < 5; ++j) k[p][j] = 0.f;
    }

    #pragma unroll 1
    for (int step = 0; step < NSTEP; ++step) {
        const float h = __shfl(h_all, step);

        #pragma unroll
        for (int p = 0; p < 2; ++p) {
            float bacc = 0.f;

            #pragma unroll 1
            for (int s = 0; s < 6; ++s) {
                // ---- stage argument for this lane's row (parity hf) ----
                float a0 = 0.f;
                #pragma unroll
                for (int j = 0; j < 5; ++j) a0 = fmaf(AT[s][j], k[p][j], a0);
                const float yt = fmaf(h, a0, y[p]);
                syt[wv][hf][d] = yt;          // 64 distinct words: 2-way = free

                float kv = 0.f;
                #pragma unroll
                for (int rw = 0; rw < 2; ++rw) {
                    // ---- m1: z = tanh(W1 . yt + b1), lane owns channels l, l+64 ----
                    float aA0 = b1A, aA1 = 0.f, aB0 = b1B, aB1 = 0.f;
                    #pragma unroll
                    for (int i = 0; i < 8; ++i) {
                        float4 yv = *(const float4*)&syt[wv][rw][4 * i];  // broadcast
                        aA0 = fmaf(W1A[4*i+0], yv.x, aA0);
                        aA1 = fmaf(W1A[4*i+1], yv.y, aA1);
                        aA0 = fmaf(W1A[4*i+2], yv.z, aA0);
                        aA1 = fmaf(W1A[4*i+3], yv.w, aA1);
                        aB0 = fmaf(W1B[4*i+0], yv.x, aB0);
                        aB1 = fmaf(W1B[4*i+1], yv.y, aB1);
                        aB0 = fmaf(W1B[4*i+2], yv.z, aB0);
                        aB1 = fmaf(W1B[4*i+3], yv.w, aB1);
                    }
                    const float zA = tanh_fast(aA0 + aA1);
                    const float zB = tanh_fast(aB0 + aB1);
                    sz[wv][rw][l]      = zA;   // banks l%32: 2-way = free
                    sz[wv][rw][64 + l] = zB;

                    // ---- m2: k[d] = W2[d] . z + b2[d], split across halves ----
                    float m0 = b2e, m1 = 0.f, m2 = 0.f, m3 = 0.f;
                    #pragma unroll
                    for (int i = 0; i < 16; ++i) {
                        float4 zv = *(const float4*)&sz[wv][rw][64 * hf + 4 * i]; // 2-addr bcast
                        m0 = fmaf(zv.x, W2R[4*i+0], m0);
                        m1 = fmaf(zv.y, W2R[4*i+1], m1);
                        m2 = fmaf(zv.z, W2R[4*i+2], m2);
                        m3 = fmaf(zv.w, W2R[4*i+3], m3);
                    }
                    float kd = (m0 + m1) + (m2 + m3);
                    kd += __shfl_xor(kd, 32);          // cross-half reduce
                    kv = (rw == hf) ? kd : kv;         // keep the k of this lane's row
                }

                // insert kv into slot s (static j, uniform compare)
                #pragma unroll
                for (int j = 0; j < 5; ++j) k[p][j] = (j == s) ? kv : k[p][j];
                bacc = fmaf(BT[s], kv, bacc);
            }

            y[p] = fmaf(h, bacc, y[p]);
            size_t r = (size_t)(rowbase + 2 * p + hf);
            out[r * (TT * DD) + (size_t)(step + 1) * DD + d] = y[p];
        }
    }
}

extern "C" void kernel_launch(void* const* d_in, const int* in_sizes, int n_in,
                              void* d_out, int out_size, void* d_ws, size_t ws_size,
                              hipStream_t stream) {
    (void)in_sizes; (void)n_in; (void)d_ws; (void)ws_size; (void)out_size;
    const float* x  = (const float*)d_in[0];
    const float* t  = (const float*)d_in[1];
    // d_in[2] = itv, d_in[3] = itv_mask : unused by the reference math
    const float* W1 = (const float*)d_in[4];
    const float* b1 = (const float*)d_in[5];
    const float* W2 = (const float*)d_in[6];
    const float* b2 = (const float*)d_in[7];
    float* out = (float*)d_out;

    dim3 grid(8192 / 16);   // 512 blocks x 4 waves x 4 rows = 8192 ODEs
    dim3 block(256);
    hipLaunchKernelGGL(NeuralODE_dopri5_regw, grid, block, 0, stream,
                       x, t, W1, b1, W2, b2, out);
}

// Round 3
// 953.127 us; speedup vs baseline: 2.7270x; 1.4804x over previous
//
#include <hip/hip_runtime.h>

#define TT 65
#define DD 32
#define HH 128
#define NSTEP 64

typedef __attribute__((ext_vector_type(8))) short bf16x8;
typedef __attribute__((ext_vector_type(4))) float f32x4;
typedef __attribute__((ext_vector_type(4))) unsigned int u32x4;

__device__ constexpr float ATc[6][5] = {
    {0.f, 0.f, 0.f, 0.f, 0.f},
    {0.2f, 0.f, 0.f, 0.f, 0.f},
    {3.f/40.f, 9.f/40.f, 0.f, 0.f, 0.f},
    {44.f/45.f, -56.f/15.f, 32.f/9.f, 0.f, 0.f},
    {19372.f/6561.f, -25360.f/2187.f, 64448.f/6561.f, -212.f/729.f, 0.f},
    {9017.f/3168.f, -355.f/33.f, 46732.f/5247.f, 49.f/176.f, -5103.f/18656.f}
};
__device__ constexpr float BTc[6] = {35.f/384.f, 0.f, 500.f/1113.f, 125.f/192.f,
                                     -2187.f/6784.f, 11.f/84.f};

struct Frag3 { bf16x8 h, m, l; };

__device__ __forceinline__ float tanh_fast(float x) {
    float e = __expf(2.0f * x);
    return 1.0f - 2.0f / (e + 1.0f);
}

// 3-term bf16 truncation split of 8 f32: v = h + m + l + O(2^-24 |v|).
// Residuals are exact (bit-slicing), packing is pure bit ops.
__device__ __forceinline__ Frag3 split8(const float* v) {
    unsigned int wh[4], wm[4], wl[4];
    #pragma unroll
    for (int p = 0; p < 4; ++p) {
        float a = v[2*p], b = v[2*p+1];
        unsigned int ua = __float_as_uint(a), ub = __float_as_uint(b);
        unsigned int uam = ua & 0xFFFF0000u, ubm = ub & 0xFFFF0000u;
        wh[p] = ubm | (ua >> 16);
        float ra = a - __uint_as_float(uam);
        float rb = b - __uint_as_float(ubm);
        unsigned int ura = __float_as_uint(ra), urb = __float_as_uint(rb);
        unsigned int uram = ura & 0xFFFF0000u, urbm = urb & 0xFFFF0000u;
        wm[p] = urbm | (ura >> 16);
        float sa = ra - __uint_as_float(uram);
        float sb = rb - __uint_as_float(urbm);
        wl[p] = (__float_as_uint(sb) & 0xFFFF0000u) | (__float_as_uint(sa) >> 16);
    }
    Frag3 f;
    u32x4 H = {wh[0], wh[1], wh[2], wh[3]};
    u32x4 M = {wm[0], wm[1], wm[2], wm[3]};
    u32x4 L = {wl[0], wl[1], wl[2], wl[3]};
    f.h = __builtin_bit_cast(bf16x8, H);
    f.m = __builtin_bit_cast(bf16x8, M);
    f.l = __builtin_bit_cast(bf16x8, L);
    return f;
}

// 6-product split accumulate: D += (H+M+L)_A * (h+m+l)_B, dropping O(2^-24) terms.
__device__ __forceinline__ f32x4 mac3(const Frag3& A, const Frag3& B, f32x4 acc) {
    acc = __builtin_amdgcn_mfma_f32_16x16x32_bf16(A.h, B.h, acc, 0, 0, 0);
    acc = __builtin_amdgcn_mfma_f32_16x16x32_bf16(A.h, B.m, acc, 0, 0, 0);
    acc = __builtin_amdgcn_mfma_f32_16x16x32_bf16(A.m, B.h, acc, 0, 0, 0);
    acc = __builtin_amdgcn_mfma_f32_16x16x32_bf16(A.h, B.l, acc, 0, 0, 0);
    acc = __builtin_amdgcn_mfma_f32_16x16x32_bf16(A.m, B.m, acc, 0, 0, 0);
    acc = __builtin_amdgcn_mfma_f32_16x16x32_bf16(A.l, B.h, acc, 0, 0, 0);
    return acc;
}

__device__ __forceinline__ f32x4 fma4s(float c, f32x4 a, f32x4 b) {  // b + c*a
    f32x4 r;
    #pragma unroll
    for (int i = 0; i < 4; ++i) r[i] = fmaf(c, a[i], b[i]);
    return r;
}

// One wave (64 threads) integrates 16 rows. Both matmuls swapped (D = W . act^T)
// so weight fragments are static MFMA A-operands held in registers/AGPRs.
// Layouts (16x16x32 bf16, verified mappings):
//   A: lane holds A[l&15][8*(l>>4)+j]   B: lane holds B[8*(l>>4)+j][l&15]
//   D: lane holds D[4*(l>>4)+reg][l&15]
// m1: D1[c][r] = W1[c][:] . yt[r][:]   (8 M-tiles over c)
// m2: D2[d][r] = W2[d][:] . z[:][r]    (2 M-tiles over d, 4 K-tiles over c)
// State y/k live in D2 layout: lane has rows r=l&15, d = 16*m2 + 4*(l>>4) + reg.
__global__ __launch_bounds__(64, 1)
void NeuralODE_dopri5_mfma(const float* __restrict__ x, const float* __restrict__ t,
                           const float* __restrict__ W1, const float* __restrict__ b1,
                           const float* __restrict__ W2, const float* __restrict__ b2,
                           float* __restrict__ out)
{
    __shared__ __align__(16) float zb[16 * 128];   // [row][ch] f32, XOR-swizzled
    __shared__ __align__(16) float ytb[16 * 32];   // [row][d]  f32, XOR-swizzled

    const int l = threadIdx.x;
    const int r = l & 15;
    const int q = l >> 4;
    const int row = blockIdx.x * 16 + r;
    const int swz = (r & 7) << 2;                  // 16B-block XOR swizzle

    // ---- static weight fragments (A-operands) ----
    Frag3 W1f[8], W2f[2][4];
    {
        float v[8];
        #pragma unroll
        for (int m = 0; m < 8; ++m) {
            *(f32x4*)&v[0] = *(const f32x4*)&W1[(16*m + r) * DD + 8*q];
            *(f32x4*)&v[4] = *(const f32x4*)&W1[(16*m + r) * DD + 8*q + 4];
            W1f[m] = split8(v);
        }
        #pragma unroll
        for (int m2 = 0; m2 < 2; ++m2)
            #pragma unroll
            for (int tt = 0; tt < 4; ++tt) {
                *(f32x4*)&v[0] = *(const f32x4*)&W2[(16*m2 + r) * HH + 32*tt + 8*q];
                *(f32x4*)&v[4] = *(const f32x4*)&W2[(16*m2 + r) * HH + 32*tt + 8*q + 4];
                W2f[m2][tt] = split8(v);
            }
    }
    // bias fragments in D layout (C-operand inits)
    f32x4 b1f[8], b2f[2];
    #pragma unroll
    for (int m = 0; m < 8; ++m) b1f[m] = *(const f32x4*)&b1[16*m + 4*q];
    #pragma unroll
    for (int m2 = 0; m2 < 2; ++m2) b2f[m2] = *(const f32x4*)&b2[16*m2 + 4*q];

    // ---- state: y in D2 layout; emit step-0 output ----
    f32x4 y[2];
    #pragma unroll
    for (int m2 = 0; m2 < 2; ++m2) {
        y[m2] = *(const f32x4*)&x[(size_t)row * (TT*DD) + 16*m2 + 4*q];
        *(f32x4*)&out[(size_t)row * (TT*DD) + 16*m2 + 4*q] = y[m2];
    }
    f32x4 kk[5][2];

    #pragma unroll 1
    for (int step = 0; step < NSTEP; ++step) {
        const float h = t[step + 1] - t[step];
        f32x4 bacc[2] = {{0,0,0,0},{0,0,0,0}};

        #pragma unroll
        for (int s = 0; s < 6; ++s) {
            // ---- stage argument yt (D2 layout) -> LDS ----
            #pragma unroll
            for (int m2 = 0; m2 < 2; ++m2) {
                f32x4 a = {0,0,0,0};
                #pragma unroll
                for (int j = 0; j < 5; ++j)
                    if (j < s) a = fma4s(ATc[s][j], kk[j][m2], a);
                f32x4 yt = fma4s(h, a, y[m2]);
                *(f32x4*)&ytb[r * 32 + ((16*m2 + 4*q) ^ swz)] = yt;
            }
            // ---- B1 fragment: yt^T slice, split 3-term ----
            float vb[8];
            *(f32x4*)&vb[0] = *(const f32x4*)&ytb[r * 32 + ((8*q)     ^ swz)];
            *(f32x4*)&vb[4] = *(const f32x4*)&ytb[r * 32 + ((8*q + 4) ^ swz)];
            Frag3 B1 = split8(vb);

            // ---- m1: z = tanh(W1 . yt + b1), 8 M-tiles ----
            f32x4 zacc[8];
            #pragma unroll
            for (int m = 0; m < 8; ++m) zacc[m] = mac3(W1f[m], B1, b1f[m]);
            #pragma unroll
            for (int m = 0; m < 8; ++m) {
                #pragma unroll
                for (int e = 0; e < 4; ++e) zacc[m][e] = tanh_fast(zacc[m][e]);
                *(f32x4*)&zb[r * 128 + ((16*m + 4*q) ^ swz)] = zacc[m];
            }
            // ---- B2 fragments: z slices, split 3-term ----
            Frag3 B2[4];
            #pragma unroll
            for (int tt = 0; tt < 4; ++tt) {
                float v2[8];
                *(f32x4*)&v2[0] = *(const f32x4*)&zb[r * 128 + ((32*tt + 8*q)     ^ swz)];
                *(f32x4*)&v2[4] = *(const f32x4*)&zb[r * 128 + ((32*tt + 8*q + 4) ^ swz)];
                B2[tt] = split8(v2);
            }
            // ---- m2: k_s = W2 . z + b2, 2 M-tiles x 4 K-tiles (separate accs) ----
            f32x4 k2[2];
            #pragma unroll
            for (int m2 = 0; m2 < 2; ++m2) {
                f32x4 zero = {0,0,0,0};
                f32x4 a0 = mac3(W2f[m2][0], B2[0], b2f[m2]);
                f32x4 a1 = mac3(W2f[m2][1], B2[1], zero);
                f32x4 a2 = mac3(W2f[m2][2], B2[2], zero);
                f32x4 a3 = mac3(W2f[m2][3], B2[3], zero);
                #pragma unroll
                for (int e = 0; e < 4; ++e) k2[m2][e] = (a0[e] + a1[e]) + (a2[e] + a3[e]);
            }
            // ---- combine ----
            #pragma unroll
            for (int m2 = 0; m2 < 2; ++m2) {
                bacc[m2] = fma4s(BTc[s], k2[m2], bacc[m2]);
                if (s < 5) kk[s][m2] = k2[m2];
            }
        }
        #pragma unroll
        for (int m2 = 0; m2 < 2; ++m2) {
            y[m2] = fma4s(h, bacc[m2], y[m2]);
            *(f32x4*)&out[(size_t)row * (TT*DD) + (size_t)(step+1) * DD + 16*m2 + 4*q] = y[m2];
        }
    }
}

extern "C" void kernel_launch(void* const* d_in, const int* in_sizes, int n_in,
                              void* d_out, int out_size, void* d_ws, size_t ws_size,
                              hipStream_t stream) {
    (void)in_sizes; (void)n_in; (void)d_ws; (void)ws_size; (void)out_size;
    const float* x  = (const float*)d_in[0];
    const float* t  = (const float*)d_in[1];
    // d_in[2] = itv, d_in[3] = itv_mask : unused by the reference math
    const float* W1 = (const float*)d_in[4];
    const float* b1 = (const float*)d_in[5];
    const float* W2 = (const float*)d_in[6];
    const float* b2 = (const float*)d_in[7];
    float* out = (float*)d_out;

    dim3 grid(8192 / 16);   // 512 waves, one wave per 16 rows
    dim3 block(64);
    hipLaunchKernelGGL(NeuralODE_dopri5_mfma, grid, block, 0, stream,
                       x, t, W1, b1, W2, b2, out);
}

// Round 4
// 446.932 us; speedup vs baseline: 5.8155x; 2.1326x over previous
//
#include <hip/hip_runtime.h>

#define TT 65
#define DD 32
#define HH 128
#define NSTEP 64

typedef __attribute__((ext_vector_type(8))) short bf16x8;
typedef __attribute__((ext_vector_type(4))) float f32x4;
typedef __attribute__((ext_vector_type(4))) unsigned int u32x4;

__device__ constexpr float ATc[6][5] = {
    {0.f, 0.f, 0.f, 0.f, 0.f},
    {0.2f, 0.f, 0.f, 0.f, 0.f},
    {3.f/40.f, 9.f/40.f, 0.f, 0.f, 0.f},
    {44.f/45.f, -56.f/15.f, 32.f/9.f, 0.f, 0.f},
    {19372.f/6561.f, -25360.f/2187.f, 64448.f/6561.f, -212.f/729.f, 0.f},
    {9017.f/3168.f, -355.f/33.f, 46732.f/5247.f, 49.f/176.f, -5103.f/18656.f}
};
__device__ constexpr float BTc[6] = {35.f/384.f, 0.f, 500.f/1113.f, 125.f/192.f,
                                     -2187.f/6784.f, 11.f/84.f};

struct Frag3 { bf16x8 h, m, l; };

__device__ __forceinline__ float tanh_fast(float x) {
    // tanh(x) = 1 - 2/(exp(2x)+1); exact at saturation, 2 trans + 3 VALU
    float e = __expf(2.0f * x);
    return fmaf(-2.0f, __builtin_amdgcn_rcpf(e + 1.0f), 1.0f);
}

// 3-term bf16 truncation split of 8 f32: v = h + m + l + O(2^-24 |v|).
__device__ __forceinline__ Frag3 split8(const float* v) {
    unsigned int wh[4], wm[4], wl[4];
    #pragma unroll
    for (int p = 0; p < 4; ++p) {
        float a = v[2*p], b = v[2*p+1];
        unsigned int ua = __float_as_uint(a), ub = __float_as_uint(b);
        unsigned int uam = ua & 0xFFFF0000u, ubm = ub & 0xFFFF0000u;
        wh[p] = ubm | (ua >> 16);
        float ra = a - __uint_as_float(uam);
        float rb = b - __uint_as_float(ubm);
        unsigned int ura = __float_as_uint(ra), urb = __float_as_uint(rb);
        unsigned int uram = ura & 0xFFFF0000u, urbm = urb & 0xFFFF0000u;
        wm[p] = urbm | (ura >> 16);
        float sa = ra - __uint_as_float(uram);
        float sb = rb - __uint_as_float(urbm);
        wl[p] = (__float_as_uint(sb) & 0xFFFF0000u) | (__float_as_uint(sa) >> 16);
    }
    Frag3 f;
    u32x4 H = {wh[0], wh[1], wh[2], wh[3]};
    u32x4 M = {wm[0], wm[1], wm[2], wm[3]};
    u32x4 L = {wl[0], wl[1], wl[2], wl[3]};
    f.h = __builtin_bit_cast(bf16x8, H);
    f.m = __builtin_bit_cast(bf16x8, M);
    f.l = __builtin_bit_cast(bf16x8, L);
    return f;
}

// 6-product split accumulate: keeps terms through 2^-16, error ~2^-24.
__device__ __forceinline__ f32x4 mac3(const Frag3& A, const Frag3& B, f32x4 acc) {
    acc = __builtin_amdgcn_mfma_f32_16x16x32_bf16(A.h, B.h, acc, 0, 0, 0);
    acc = __builtin_amdgcn_mfma_f32_16x16x32_bf16(A.h, B.m, acc, 0, 0, 0);
    acc = __builtin_amdgcn_mfma_f32_16x16x32_bf16(A.m, B.h, acc, 0, 0, 0);
    acc = __builtin_amdgcn_mfma_f32_16x16x32_bf16(A.h, B.l, acc, 0, 0, 0);
    acc = __builtin_amdgcn_mfma_f32_16x16x32_bf16(A.m, B.m, acc, 0, 0, 0);
    acc = __builtin_amdgcn_mfma_f32_16x16x32_bf16(A.l, B.h, acc, 0, 0, 0);
    return acc;
}

// Block = 4 waves = 16 ODE rows. Per stage, wave w:
//   m1 tiles {2w,2w+1} -> z channels [32w,32w+32) -> own K=32 slice of m2 -> partial.
//   barrier; wave w owns state d-slice [8w,8w+8) (2 values/lane): reduce 4
//   partials, update y/k, write next stage argument slice to ytb; barrier.
// MFMA 16x16x32 layouts (verified R3): A: lane=(q,r) holds A[r][8q+j];
// B: B[8q+j][r]; D: D[4q+e][r]. All LDS rows are 32 floats, XOR-swizzled by
// ((r&7)<<2) at 4-float granularity -> <=2-way (free) bank aliasing.
__global__ __launch_bounds__(256, 2)
void NeuralODE_dopri5_mw(const float* __restrict__ x, const float* __restrict__ t,
                         const float* __restrict__ W1, const float* __restrict__ b1,
                         const float* __restrict__ W2, const float* __restrict__ b2,
                         float* __restrict__ out)
{
    __shared__ __align__(16) float ytb[16 * 32];        // stage argument, B1-source
    __shared__ __align__(16) float zb [4][16 * 32];     // per-wave private z bounce
    __shared__ __align__(16) float pb [4][16 * 32];     // m2 partials per wave

    const int tid = threadIdx.x;
    const int w   = tid >> 6;
    const int l   = tid & 63;
    const int r   = l & 15;
    const int q   = l >> 4;
    const int swz = (r & 7) << 2;
    const int row = blockIdx.x * 16 + r;
    const int d0  = 8 * w + 2 * q;                      // owned d-slice pair

    // ---- static weight fragments ----
    Frag3 W1f[2], W2f[2];
    f32x4 b1f[2];
    {
        float v[8];
        #pragma unroll
        for (int i = 0; i < 2; ++i) {
            int m = 2 * w + i;
            *(f32x4*)&v[0] = *(const f32x4*)&W1[(16*m + r) * DD + 8*q];
            *(f32x4*)&v[4] = *(const f32x4*)&W1[(16*m + r) * DD + 8*q + 4];
            W1f[i] = split8(v);
            b1f[i] = *(const f32x4*)&b1[16*m + 4*q];
        }
        #pragma unroll
        for (int m2 = 0; m2 < 2; ++m2) {
            *(f32x4*)&v[0] = *(const f32x4*)&W2[(16*m2 + r) * HH + 32*w + 8*q];
            *(f32x4*)&v[4] = *(const f32x4*)&W2[(16*m2 + r) * HH + 32*w + 8*q + 4];
            W2f[m2] = split8(v);
        }
    }
    const float b2x = b2[d0], b2y = b2[d0 + 1];

    // ---- state slice: y[d0], y[d0+1] for row r ----
    float yx, yy;
    {
        float2 y0 = *(const float2*)&x[(size_t)row * (TT*DD) + d0];
        yx = y0.x; yy = y0.y;
        *(float2*)&ytb[r * 32 + (d0 ^ swz)] = y0;       // stage-0 argument
        *(float2*)&out[(size_t)row * (TT*DD) + d0] = y0; // step-0 output
    }
    float kxs[5], kys[5];
    __syncthreads();

    #pragma unroll 1
    for (int step = 0; step < NSTEP; ++step) {
        const float h = t[step + 1] - t[step];
        float bax = 0.f, bay = 0.f;

        #pragma unroll
        for (int s = 0; s < 6; ++s) {
            // ---- B1 fragment (full yt row r) ----
            float vb[8];
            *(f32x4*)&vb[0] = *(const f32x4*)&ytb[r * 32 + ((8*q)     ^ swz)];
            *(f32x4*)&vb[4] = *(const f32x4*)&ytb[r * 32 + ((8*q + 4) ^ swz)];
            Frag3 B1 = split8(vb);

            // ---- m1: 2 of 8 tiles, + tanh ----
            f32x4 z0 = mac3(W1f[0], B1, b1f[0]);
            f32x4 z1 = mac3(W1f[1], B1, b1f[1]);
            #pragma unroll
            for (int e = 0; e < 4; ++e) { z0[e] = tanh_fast(z0[e]); z1[e] = tanh_fast(z1[e]); }

            // ---- z bounce D->B within own slice (private region) ----
            *(f32x4*)&zb[w][r * 32 + ((     4*q) ^ swz)] = z0;
            *(f32x4*)&zb[w][r * 32 + ((16 + 4*q) ^ swz)] = z1;
            float vz[8];
            *(f32x4*)&vz[0] = *(const f32x4*)&zb[w][r * 32 + ((8*q)     ^ swz)];
            *(f32x4*)&vz[4] = *(const f32x4*)&zb[w][r * 32 + ((8*q + 4) ^ swz)];
            Frag3 B2 = split8(vz);

            // ---- m2 partial over K-slice [32w,32w+32), both d-tiles ----
            const f32x4 zero = {0.f, 0.f, 0.f, 0.f};
            f32x4 p0 = mac3(W2f[0], B2, zero);
            f32x4 p1 = mac3(W2f[1], B2, zero);
            *(f32x4*)&pb[w][r * 32 + ((     4*q) ^ swz)] = p0;
            *(f32x4*)&pb[w][r * 32 + ((16 + 4*q) ^ swz)] = p1;
            __syncthreads();

            // ---- reduce own d-slice over 4 partials (+ bias) ----
            float kx = b2x, ky = b2y;
            #pragma unroll
            for (int v4 = 0; v4 < 4; ++v4) {
                float2 pp = *(const float2*)&pb[v4][r * 32 + (d0 ^ swz)];
                kx += pp.x; ky += pp.y;
            }
            if (s < 5) { kxs[s] = kx; kys[s] = ky; }
            bax = fmaf(BTc[s], kx, bax);
            bay = fmaf(BTc[s], ky, bay);

            if (s < 5) {
                // next stage argument slice: yt = y + h * sum_j A[s+1][j] k_j
                float ax = ATc[s+1][s] * kx;
                float ay = ATc[s+1][s] * ky;
                #pragma unroll
                for (int j = 0; j < 5; ++j)
                    if (j < s) { ax = fmaf(ATc[s+1][j], kxs[j], ax);
                                 ay = fmaf(ATc[s+1][j], kys[j], ay); }
                float2 yt = { fmaf(h, ax, yx), fmaf(h, ay, yy) };
                *(float2*)&ytb[r * 32 + (d0 ^ swz)] = yt;
            } else {
                yx = fmaf(h, bax, yx);
                yy = fmaf(h, bay, yy);
                float2 yn = {yx, yy};
                *(float2*)&ytb[r * 32 + (d0 ^ swz)] = yn;   // stage-0 arg of next step
                *(float2*)&out[(size_t)row * (TT*DD) + (size_t)(step+1) * DD + d0] = yn;
            }
            __syncthreads();
        }
    }
}

extern "C" void kernel_launch(void* const* d_in, const int* in_sizes, int n_in,
                              void* d_out, int out_size, void* d_ws, size_t ws_size,
                              hipStream_t stream) {
    (void)in_sizes; (void)n_in; (void)d_ws; (void)ws_size; (void)out_size;
    const float* x  = (const float*)d_in[0];
    const float* t  = (const float*)d_in[1];
    // d_in[2] = itv, d_in[3] = itv_mask : unused by the reference math
    const float* W1 = (const float*)d_in[4];
    const float* b1 = (const float*)d_in[5];
    const float* W2 = (const float*)d_in[6];
    const float* b2 = (const float*)d_in[7];
    float* out = (float*)d_out;

    dim3 grid(8192 / 16);   // 512 blocks x 4 waves = 2048 waves (8/CU, 2/SIMD)
    dim3 block(256);
    hipLaunchKernelGGL(NeuralODE_dopri5_mw, grid, block, 0, stream,
                       x, t, W1, b1, W2, b2, out);
}